// Round 6
// baseline (439.879 us; speedup 1.0000x reference)
//
#include <hip/hip_runtime.h>
#include <hip/hip_bf16.h>

typedef unsigned short u16;
typedef unsigned int   u32;

typedef __attribute__((ext_vector_type(8))) short bf16x8;  // 8 bf16 = 4 VGPRs
typedef __attribute__((ext_vector_type(4))) float f32x4;   // MFMA 16x16 accum

constexpr int N_AUDIO = 480000;
constexpr int K_IR    = 240000;

// Block tile: 16384 outputs (4 waves x MT4 x NT4 x 256). K split across blocks.
constexpr int NSPLIT  = 34;
constexpr int LSPLIT  = 7296;             // 34*7296 = 248064 >= 240783 (K+15+768)
constexpr int BK      = 384;              // taps per LDS chunk
constexpr int NCHUNK  = LSPLIT / BK;      // 19
constexpr int NGROUP  = 30;               // ceil(480000/16384)

// LDS window per chunk: elems [k0c-776, k0c+408) per phase row = 1184 elems
constexpr int WIN_CH  = 148;              // 1184/8  16B-chunks along k
constexpr int NITEM   = WIN_CH * 8;       // 1184 16B items (phase-interleaved)

// padded bf16 audio (max read 735728)
constexpr int A_ELEMS = 737280;
// IR phase rows: row p holds ir_p[x] = ir[x-p], x in [-IR_PAD, ROW_IR-IR_PAD)
constexpr int IR_PAD  = 784;
constexpr int ROW_IR  = 248880;           // >= 784 + 248088, mult of 16
constexpr int IR_ELEMS = 8 * ROW_IR;      // 1,991,040

// ws layout (bytes), all 16B aligned
constexpr size_t OFF_A   = 0;
constexpr size_t OFF_IR  = (size_t)A_ELEMS * 2;              // 1,474,560
constexpr size_t OFF_ACC = OFF_IR + (size_t)IR_ELEMS * 2;    // 5,456,640
constexpr size_t OFF_MAX = OFF_ACC + (size_t)N_AUDIO * 4;    // 7,376,640

__device__ __forceinline__ u16 f2bf(float f) {
    u32 u = __float_as_uint(f);
    u32 r = (u + 0x7fffu + ((u >> 16) & 1u)) >> 16;   // RTN
    return (u16)r;
}

// ---- kernel 1: convert inputs to bf16 (audio padded, IR in 8 phase rows), zero accum+slot
__global__ void prep_kernel(const float* __restrict__ audio, const float* __restrict__ ir,
                            u16* __restrict__ abuf, u16* __restrict__ irbuf,
                            float* __restrict__ accum, u32* __restrict__ slot) {
    int tid = blockIdx.x * blockDim.x + threadIdx.x;
    int nth = gridDim.x * blockDim.x;
    if (tid == 0) *slot = 0u;
    for (int i = tid; i < A_ELEMS; i += nth)
        abuf[i] = (i < N_AUDIO) ? f2bf(audio[i]) : (u16)0;
    for (int i = tid; i < IR_ELEMS; i += nth) {
        int p = i / ROW_IR;               // phase 0..7
        int x = (i - p * ROW_IR) - IR_PAD;
        int src = x - p;
        irbuf[i] = (src >= 0 && src < K_IR) ? f2bf(ir[src]) : (u16)0;
    }
    for (int i = tid; i < N_AUDIO; i += nth) accum[i] = 0.0f;
}

// ---- kernel 2: MFMA correlation. Block = 4 waves, same (s,g), 16384 outputs.
// IR (8 phase rows) double-buffered in LDS per 384-tap chunk via async
// global_load_lds DMA (zero staging VGPRs); A from global (immediate-offset
// b128 loads). Per wave: MT=4 x NT=4 (4096 outputs). Split-K atomicAdd epilogue.
// launch_bounds(256,4): 64 acc AGPR + <=64 VGPR -> 4 waves/SIMD.
__global__ __launch_bounds__(256, 4) void conv_kernel(const u16* __restrict__ abuf,
                                                      const u16* __restrict__ irbuf,
                                                      float* __restrict__ accum) {
    // phase-interleaved: item idx = kchunk*8 + phase, 16B each
    __shared__ u16 lbuf[2][NITEM * 8];    // 2 x 18,944 B

    const int tid  = threadIdx.x;
    const int wave = tid >> 6;
    const int lane = tid & 63;
    const int bid  = blockIdx.x;
    const int s    = bid / NGROUP;                   // k-split 0..33
    const int g    = bid - s * NGROUP;               // output group 0..29

    const int m16 = lane & 15;                       // A row m / B col n / C col
    const int kq  = lane >> 4;                       // 0..3 (k-chunk quadrant)
    const int nh  = m16 >> 3;                        // n high bit
    const int ph  = m16 & 7;                         // IR phase row

    const int k0 = s * LSPLIT;

    // A base: audio[g*16384 + wave*4096 + 16*m + 8*kq + k]
    const u16* aptr0 = abuf + g * 16384 + wave * 4096 + 16 * m16 + 8 * kq + k0;
    // staging source: item idx -> phase p=idx&7, kchunk cc=idx>>3
    // global elem = p*ROW_IR + (IR_PAD-776) + k0 + chunk*BK + 8*cc   (16B aligned)
    const u16* irb = irbuf + (IR_PAD - 776) + k0;

    // per-thread staging item (fixed across chunks)
    const int i_p  = tid & 7;
    const int i_cc = tid >> 3;

    auto stage = [&](int c, int buf) {
        #pragma unroll
        for (int r = 0; r < 5; ++r) {
            int idx = tid + 256 * r;
            if (idx < NITEM) {
                int p  = idx & 7;
                int cc = idx >> 3;
                const u16* gp = irb + (size_t)p * ROW_IR + c * BK + 8 * cc;
                __builtin_amdgcn_global_load_lds(
                    (const __attribute__((address_space(1))) u32*)gp,
                    (__attribute__((address_space(3))) u32*)&lbuf[buf][idx * 8],
                    16, 0, 0);
            }
        }
    };
    (void)i_p; (void)i_cc;

    f32x4 acc[4][4];
    #pragma unroll
    for (int mt = 0; mt < 4; ++mt)
        #pragma unroll
        for (int nt = 0; nt < 4; ++nt)
            acc[mt][nt] = (f32x4){0.f, 0.f, 0.f, 0.f};

    // prologue: stage chunk 0 into buffer 0
    stage(0, 0);
    __syncthreads();

    for (int c = 0; c < NCHUNK; ++c) {
        const int cur = c & 1;
        // async-stage chunk c+1 into the other buffer (drained by the barrier)
        if (c + 1 < NCHUNK) stage(c + 1, cur ^ 1);

        // compute: 12 k-steps of 32 taps from lbuf[cur]
        const u16* ap = aptr0 + c * BK;
        const u16* lb = &lbuf[cur][((kq - nh) * 8 + ph) * 8];  // lane-invariant part via imm
        #pragma unroll
        for (int it2 = 0; it2 < BK / 32; ++it2) {
            bf16x8 b[4], a[4];
            #pragma unroll
            for (int nt = 0; nt < 4; ++nt) {
                // ch = 97 + 4*it2 + (kq-nh) - 32*nt ; u16 offset = ch*64 + ph*8
                b[nt] = *(const bf16x8*)(lb + (97 + 4 * it2 - 32 * nt) * 64);
            }
            #pragma unroll
            for (int mt = 0; mt < 4; ++mt)
                a[mt] = *(const bf16x8*)(ap + 1024 * mt + 32 * it2);
            #pragma unroll
            for (int mt = 0; mt < 4; ++mt)
                #pragma unroll
                for (int nt = 0; nt < 4; ++nt)
                    acc[mt][nt] = __builtin_amdgcn_mfma_f32_16x16x32_bf16(a[mt], b[nt], acc[mt][nt], 0, 0, 0);
        }
        __syncthreads();
    }

    // epilogue: C/D layout col = lane&15, row = kq*4 + r -> t = base + 16*row + col
    const int gbase_w = g * 16384 + wave * 4096;
    #pragma unroll
    for (int mt = 0; mt < 4; ++mt) {
        #pragma unroll
        for (int nt = 0; nt < 4; ++nt) {
            int base = gbase_w + 1024 * mt + 256 * nt + 64 * kq + m16;
            #pragma unroll
            for (int r = 0; r < 4; ++r) {
                int t = base + 16 * r;
                if (t < N_AUDIO) atomicAdd(&accum[t], acc[mt][nt][r]);
            }
        }
    }
}

// ---- kernel 3: global abs-max (float-bits atomicMax works for non-negative floats)
__global__ __launch_bounds__(256) void reduce_max_kernel(const float* __restrict__ accum,
                                                         u32* __restrict__ slot) {
    int tid = blockIdx.x * blockDim.x + threadIdx.x;
    int nth = gridDim.x * blockDim.x;
    float m = 0.f;
    for (int i = tid; i < N_AUDIO; i += nth) m = fmaxf(m, fabsf(accum[i]));
    for (int off = 32; off > 0; off >>= 1) m = fmaxf(m, __shfl_down(m, off, 64));
    __shared__ float smax[4];
    if ((threadIdx.x & 63) == 0) smax[threadIdx.x >> 6] = m;
    __syncthreads();
    if (threadIdx.x == 0) {
        float b = fmaxf(fmaxf(smax[0], smax[1]), fmaxf(smax[2], smax[3]));
        atomicMax(slot, __float_as_uint(b));
    }
}

// ---- kernel 4: normalize
__global__ __launch_bounds__(256) void scale_kernel(const float* __restrict__ accum,
                                                    const u32* __restrict__ slot,
                                                    float* __restrict__ out) {
    float inv = 1.0f / __uint_as_float(*slot);
    int t = blockIdx.x * 256 + threadIdx.x;
    if (t < N_AUDIO) out[t] = accum[t] * inv;
}

extern "C" void kernel_launch(void* const* d_in, const int* in_sizes, int n_in,
                              void* d_out, int out_size, void* d_ws, size_t ws_size,
                              hipStream_t stream) {
    const float* audio = (const float*)d_in[0];
    const float* ir    = (const float*)d_in[1];
    float* out = (float*)d_out;

    char* ws = (char*)d_ws;
    u16*   abuf  = (u16*)(ws + OFF_A);
    u16*   irbuf = (u16*)(ws + OFF_IR);
    float* accum = (float*)(ws + OFF_ACC);
    u32*   slot  = (u32*)(ws + OFF_MAX);

    prep_kernel<<<2048, 256, 0, stream>>>(audio, ir, abuf, irbuf, accum, slot);
    conv_kernel<<<NGROUP * NSPLIT, 256, 0, stream>>>(abuf, irbuf, accum);
    reduce_max_kernel<<<960, 256, 0, stream>>>(accum, slot);
    scale_kernel<<<(N_AUDIO + 255) / 256, 256, 0, stream>>>(accum, slot, out);
}

// Round 7
// 262.041 us; speedup vs baseline: 1.6787x; 1.6787x over previous
//
#include <hip/hip_runtime.h>
#include <hip/hip_bf16.h>

typedef unsigned short u16;
typedef unsigned int   u32;

typedef __attribute__((ext_vector_type(8))) short bf16x8;  // 8 bf16 = 4 VGPRs
typedef __attribute__((ext_vector_type(4))) float f32x4;   // MFMA 16x16 accum

constexpr int N_AUDIO = 480000;
constexpr int K_IR    = 240000;

// Block tile: 16384 outputs (4 waves x MT4 x NT4 x 256). K split across blocks.
constexpr int NSPLIT  = 34;
constexpr int LSPLIT  = 7296;             // 34*7296 = 248064 >= 240783 (K+15+768)
constexpr int BK      = 384;              // taps per LDS chunk
constexpr int NCHUNK  = LSPLIT / BK;      // 19
constexpr int NGROUP  = 30;               // ceil(480000/16384)

// LDS window per chunk: elems [k0c-776, k0c+408) per phase row = 1184 elems
constexpr int WIN_CH  = 148;              // 1184/8  16B-chunks along k
constexpr int NITEM   = WIN_CH * 8;       // 1184 16B items (phase-interleaved)

// padded bf16 audio (max read 735728)
constexpr int A_ELEMS = 737280;
// IR phase rows: row p holds ir_p[x] = ir[x-p], x in [-IR_PAD, ROW_IR-IR_PAD)
constexpr int IR_PAD  = 784;
constexpr int ROW_IR  = 248880;           // >= 784 + 248088, mult of 16
constexpr int IR_ELEMS = 8 * ROW_IR;      // 1,991,040

// ws layout (bytes), all 16B aligned
constexpr size_t OFF_A   = 0;
constexpr size_t OFF_IR  = (size_t)A_ELEMS * 2;              // 1,474,560
constexpr size_t OFF_ACC = OFF_IR + (size_t)IR_ELEMS * 2;    // 5,456,640
constexpr size_t OFF_MAX = OFF_ACC + (size_t)N_AUDIO * 4;    // 7,376,640

__device__ __forceinline__ u16 f2bf(float f) {
    u32 u = __float_as_uint(f);
    u32 r = (u + 0x7fffu + ((u >> 16) & 1u)) >> 16;   // RTN
    return (u16)r;
}

// ---- kernel 1: convert inputs to bf16 (audio padded, IR in 8 phase rows), zero accum+slot
__global__ void prep_kernel(const float* __restrict__ audio, const float* __restrict__ ir,
                            u16* __restrict__ abuf, u16* __restrict__ irbuf,
                            float* __restrict__ accum, u32* __restrict__ slot) {
    int tid = blockIdx.x * blockDim.x + threadIdx.x;
    int nth = gridDim.x * blockDim.x;
    if (tid == 0) *slot = 0u;
    for (int i = tid; i < A_ELEMS; i += nth)
        abuf[i] = (i < N_AUDIO) ? f2bf(audio[i]) : (u16)0;
    for (int i = tid; i < IR_ELEMS; i += nth) {
        int p = i / ROW_IR;               // phase 0..7
        int x = (i - p * ROW_IR) - IR_PAD;
        int src = x - p;
        irbuf[i] = (src >= 0 && src < K_IR) ? f2bf(ir[src]) : (u16)0;
    }
    for (int i = tid; i < N_AUDIO; i += nth) accum[i] = 0.0f;
}

// ---- kernel 2: MFMA correlation. Block = 4 waves, same (s,g), 16384 outputs.
// IR (8 phase rows) double-buffered in LDS per 384-tap chunk via async
// global_load_lds DMA (zero staging VGPRs, no commit loop); A from global.
// Per wave: MT=4 x NT=4 (4096 outputs). Split-K atomicAdd epilogue.
// R6 lesson: do NOT cap regs at 128 (spill); (256,3) + unroll 2 fits in ~140.
__global__ __launch_bounds__(256, 3) void conv_kernel(const u16* __restrict__ abuf,
                                                      const u16* __restrict__ irbuf,
                                                      float* __restrict__ accum) {
    // phase-interleaved: item idx = kchunk*8 + phase, 16B each
    __shared__ u16 lbuf[2][NITEM * 8];    // 2 x 18,944 B

    const int tid  = threadIdx.x;
    const int wave = tid >> 6;
    const int lane = tid & 63;
    const int bid  = blockIdx.x;
    const int s    = bid / NGROUP;                   // k-split 0..33
    const int g    = bid - s * NGROUP;               // output group 0..29

    const int m16 = lane & 15;                       // A row m / B col n / C col
    const int kq  = lane >> 4;                       // 0..3 (k-chunk quadrant)
    const int nh  = m16 >> 3;                        // n high bit
    const int ph  = m16 & 7;                         // IR phase row

    const int k0 = s * LSPLIT;

    // A base: audio[g*16384 + wave*4096 + 16*m + 8*kq + k]
    const u16* aptr0 = abuf + g * 16384 + wave * 4096 + 16 * m16 + 8 * kq + k0;
    // staging source: item idx -> phase p=idx&7, kchunk cc=idx>>3
    // global elem = p*ROW_IR + (IR_PAD-776) + k0 + chunk*BK + 8*cc   (16B aligned)
    const u16* irb = irbuf + (IR_PAD - 776) + k0;

    auto stage = [&](int c, int buf) {
        #pragma unroll
        for (int r = 0; r < 5; ++r) {
            int idx = tid + 256 * r;
            if (idx < NITEM) {
                int p  = idx & 7;
                int cc = idx >> 3;
                const u16* gp = irb + (size_t)p * ROW_IR + c * BK + 8 * cc;
                __builtin_amdgcn_global_load_lds(
                    (const __attribute__((address_space(1))) u32*)gp,
                    (__attribute__((address_space(3))) u32*)&lbuf[buf][idx * 8],
                    16, 0, 0);
            }
        }
    };

    f32x4 acc[4][4];
    #pragma unroll
    for (int mt = 0; mt < 4; ++mt)
        #pragma unroll
        for (int nt = 0; nt < 4; ++nt)
            acc[mt][nt] = (f32x4){0.f, 0.f, 0.f, 0.f};

    // prologue: stage chunk 0 into buffer 0
    stage(0, 0);
    __syncthreads();

    for (int c = 0; c < NCHUNK; ++c) {
        const int cur = c & 1;
        // async-stage chunk c+1 into the other buffer (drained by the barrier)
        if (c + 1 < NCHUNK) stage(c + 1, cur ^ 1);

        // compute: 12 k-steps of 32 taps from lbuf[cur]
        const u16* ap = aptr0 + c * BK;
        const u16* lb = &lbuf[cur][((kq - nh) * 8 + ph) * 8];  // lane part; rest imm
        #pragma unroll 2
        for (int it2 = 0; it2 < BK / 32; ++it2) {
            bf16x8 b[4], a[4];
            #pragma unroll
            for (int nt = 0; nt < 4; ++nt) {
                // ch = 97 + 4*it2 + (kq-nh) - 32*nt ; u16 offset = ch*64 + ph*8
                b[nt] = *(const bf16x8*)(lb + (97 + 4 * it2 - 32 * nt) * 64);
            }
            #pragma unroll
            for (int mt = 0; mt < 4; ++mt)
                a[mt] = *(const bf16x8*)(ap + 1024 * mt + 32 * it2);
            #pragma unroll
            for (int mt = 0; mt < 4; ++mt)
                #pragma unroll
                for (int nt = 0; nt < 4; ++nt)
                    acc[mt][nt] = __builtin_amdgcn_mfma_f32_16x16x32_bf16(a[mt], b[nt], acc[mt][nt], 0, 0, 0);
        }
        __syncthreads();
    }

    // epilogue: C/D layout col = lane&15, row = kq*4 + r -> t = base + 16*row + col
    const int gbase_w = g * 16384 + wave * 4096;
    #pragma unroll
    for (int mt = 0; mt < 4; ++mt) {
        #pragma unroll
        for (int nt = 0; nt < 4; ++nt) {
            int base = gbase_w + 1024 * mt + 256 * nt + 64 * kq + m16;
            #pragma unroll
            for (int r = 0; r < 4; ++r) {
                int t = base + 16 * r;
                if (t < N_AUDIO) atomicAdd(&accum[t], acc[mt][nt][r]);
            }
        }
    }
}

// ---- kernel 3: global abs-max (float-bits atomicMax works for non-negative floats)
__global__ __launch_bounds__(256) void reduce_max_kernel(const float* __restrict__ accum,
                                                         u32* __restrict__ slot) {
    int tid = blockIdx.x * blockDim.x + threadIdx.x;
    int nth = gridDim.x * blockDim.x;
    float m = 0.f;
    for (int i = tid; i < N_AUDIO; i += nth) m = fmaxf(m, fabsf(accum[i]));
    for (int off = 32; off > 0; off >>= 1) m = fmaxf(m, __shfl_down(m, off, 64));
    __shared__ float smax[4];
    if ((threadIdx.x & 63) == 0) smax[threadIdx.x >> 6] = m;
    __syncthreads();
    if (threadIdx.x == 0) {
        float b = fmaxf(fmaxf(smax[0], smax[1]), fmaxf(smax[2], smax[3]));
        atomicMax(slot, __float_as_uint(b));
    }
}

// ---- kernel 4: normalize
__global__ __launch_bounds__(256) void scale_kernel(const float* __restrict__ accum,
                                                    const u32* __restrict__ slot,
                                                    float* __restrict__ out) {
    float inv = 1.0f / __uint_as_float(*slot);
    int t = blockIdx.x * 256 + threadIdx.x;
    if (t < N_AUDIO) out[t] = accum[t] * inv;
}

extern "C" void kernel_launch(void* const* d_in, const int* in_sizes, int n_in,
                              void* d_out, int out_size, void* d_ws, size_t ws_size,
                              hipStream_t stream) {
    const float* audio = (const float*)d_in[0];
    const float* ir    = (const float*)d_in[1];
    float* out = (float*)d_out;

    char* ws = (char*)d_ws;
    u16*   abuf  = (u16*)(ws + OFF_A);
    u16*   irbuf = (u16*)(ws + OFF_IR);
    float* accum = (float*)(ws + OFF_ACC);
    u32*   slot  = (u32*)(ws + OFF_MAX);

    prep_kernel<<<2048, 256, 0, stream>>>(audio, ir, abuf, irbuf, accum, slot);
    conv_kernel<<<NGROUP * NSPLIT, 256, 0, stream>>>(abuf, irbuf, accum);
    reduce_max_kernel<<<960, 256, 0, stream>>>(accum, slot);
    scale_kernel<<<(N_AUDIO + 255) / 256, 256, 0, stream>>>(accum, slot, out);
}

// Round 8
// 123.718 us; speedup vs baseline: 3.5555x; 2.1181x over previous
//
#include <hip/hip_runtime.h>
#include <hip/hip_bf16.h>

typedef unsigned int u32;

// ---------------- FFT-based reverb ----------------
// out[t] = sum_k audio[t+k] ir[k]  (correlation), t in [0, 480000)
// M = 2^20 circular: t+k <= 719998 < M  -> equals linear result.
// Pack: z = a + i*b ; Z = F[z]; A=(Z[f]+conj(Z[M-f]))/2, B=(Z[f]-conj(Z[M-f]))/(2i)
// S = A*conj(B)  (F[corr] = F[a]*conj(F[b]) for real b)
// out = Re( F[ conj(S)/M ] )   (inverse-FFT via conjugation trick)
//
// Four-step: M = R*C = 1024*1024, n = c*1024 + r, k = k1 + 1024*k2.
// pass1: for each r: F_r[k1] = FFT_1024_c{ x[c*1024+r] } * W_M^{r*k1}, store buf[r*1024+k1]
// pass2: for each k1: X[k1+1024*k2] = FFT_1024_r{ buf[r*1024+k1] }, store spec[k1*1024+k2]
// s-layout spec[k1*1024+k2] makes transform-2's pass1 gather CONTIGUOUS:
//   u[c2*1024+r2] = T[f=c2*1024+r2] = stored[r2*1024+c2].

constexpr int N_AUDIO = 480000;
constexpr int K_IR    = 240000;
constexpr int M_FFT   = 1048576;      // 2^20

constexpr size_t OFF_C0   = 0;                    // 8 MB float2
constexpr size_t OFF_C1   = (size_t)M_FFT * 8;    // 8 MB float2
constexpr size_t OFF_SLOT = OFF_C1 + (size_t)M_FFT * 8;   // u32

__device__ __forceinline__ float2 cmul(float2 a, float2 b) {
    return make_float2(a.x * b.x - a.y * b.y, a.x * b.y + a.y * b.x);
}
__device__ __forceinline__ float2 twid(float frac) {   // e^{-2*pi*i*frac}
    float s, c;
    __sincosf(-6.28318530717958647692f * frac, &s, &c);
    return make_float2(c, s);
}

// radix-2 Stockham FFT-1024 in LDS, 2 rows concurrently, 256 threads.
// Invariant after stage s (L=2^s before stage): A[q*L+k] = FFT_L of subseq
// (start q, stride n/L). Butterfly: reads tid, tid+512; writes 2*tid-k, +L.
// 10 stages (even) -> result lands back in src. Verified by hand at n=4.
__device__ __forceinline__ void fft1024x2(float2 (*src)[1024], float2 (*scr)[1024], int t) {
    float2 (*A)[1024] = src;
    float2 (*B)[1024] = scr;
    #pragma unroll
    for (int s = 0; s < 10; ++s) {
        const int L = 1 << s;
        #pragma unroll
        for (int h = 0; h < 2; ++h) {
            const int tid = t + 256 * h;
            const int k   = tid & (L - 1);
            const float2 w = twid((float)k / (float)(2 * L));
            const int o0  = 2 * tid - k;
            #pragma unroll
            for (int j = 0; j < 2; ++j) {
                float2 x0 = A[j][tid];
                float2 x1 = A[j][tid + 512];
                float2 t1 = cmul(w, x1);
                B[j][o0]     = make_float2(x0.x + t1.x, x0.y + t1.y);
                B[j][o0 + L] = make_float2(x0.x - t1.x, x0.y - t1.y);
            }
        }
        __syncthreads();
        float2 (*tmp)[1024] = A; A = B; B = tmp;
    }
}

// ---- kernel 1: z = audio + i*ir, zero-padded; zero slot
__global__ __launch_bounds__(256) void prep_z(const float* __restrict__ a,
                                              const float* __restrict__ b,
                                              float2* __restrict__ z,
                                              u32* __restrict__ slot) {
    int i = blockIdx.x * 256 + threadIdx.x;
    if (i == 0) *slot = 0u;
    if (i < M_FFT) {
        float xr = (i < N_AUDIO) ? a[i] : 0.0f;
        float xi = (i < K_IR)    ? b[i] : 0.0f;
        z[i] = make_float2(xr, xi);
    }
}

// ---- pass 1 (row FFTs + inter-pass twiddle). 2 rows per block.
// STRIDED: input x[c*1024 + r] (transform 1); else x[r*1024 + c] (transform 2).
template<bool STRIDED>
__global__ __launch_bounds__(256) void fft_pass1(const float2* __restrict__ in,
                                                 float2* __restrict__ outb) {
    __shared__ float2 rows[2][1024];
    __shared__ float2 scr [2][1024];
    const int t  = threadIdx.x;
    const int r0 = blockIdx.x * 2;
    if (STRIDED) {
        const int j = t & 1, bc = t >> 1;
        #pragma unroll
        for (int q = 0; q < 8; ++q) {
            int c = bc + 128 * q;
            rows[j][c] = in[c * 1024 + r0 + j];
        }
    } else {
        #pragma unroll
        for (int q = 0; q < 8; ++q) {
            int idx = t + 256 * q;               // j*1024 + c
            rows[idx >> 10][idx & 1023] = in[r0 * 1024 + idx];
        }
    }
    __syncthreads();
    fft1024x2(rows, scr, t);
    // result in rows[j][k1]; twiddle W_M^{(r0+j)*k1}, store outb[(r0+j)*1024+k1]
    #pragma unroll
    for (int q = 0; q < 8; ++q) {
        int idx = t + 256 * q;                   // j*1024 + k1
        int j = idx >> 10, k1 = idx & 1023;
        float frac = (float)((r0 + j) * k1) * (1.0f / 1048576.0f);  // < 2^24 exact
        outb[r0 * 1024 + idx] = cmul(twid(frac), rows[j][k1]);
    }
}

// ---- pass 2 of transform 1: column FFTs, store spec in s-layout
__global__ __launch_bounds__(256) void fft_pass2_store(const float2* __restrict__ in,
                                                       float2* __restrict__ spec) {
    __shared__ float2 cols[2][1024];
    __shared__ float2 scr [2][1024];
    const int t  = threadIdx.x;
    const int c0 = blockIdx.x * 2;
    const int j = t & 1, br = t >> 1;
    #pragma unroll
    for (int q = 0; q < 8; ++q) {
        int r = br + 128 * q;
        cols[j][r] = in[r * 1024 + c0 + j];
    }
    __syncthreads();
    fft1024x2(cols, scr, t);
    #pragma unroll
    for (int q = 0; q < 8; ++q) {
        int idx = t + 256 * q;                   // j*1024 + k2
        spec[c0 * 1024 + idx] = cols[idx >> 10][idx & 1023];
    }
}

// ---- pointwise (in place): spec -> T = conj(S)/M,  S = A*conj(B)
__global__ __launch_bounds__(256) void pointwise(float2* __restrict__ sp) {
    int s = blockIdx.x * 256 + threadIdx.x;      // s = k1*1024 + k2  <->  f = k1 + 1024*k2
    int k1 = s >> 10, k2 = s & 1023;
    int k1p = (k1 == 0) ? 0 : 1024 - k1;
    int k2p = (k1 == 0) ? ((1024 - k2) & 1023) : 1023 - k2;
    int sp_ = k1p * 1024 + k2p;                  // storage index of M-f
    const float invM = 1.0f / 1048576.0f;
    if (s == sp_) {                              // f = 0 or M/2: Z = (A_real, B_real)
        float2 z = sp[s];
        sp[s] = make_float2(z.x * z.y * invM, 0.0f);
    } else if (s < sp_) {
        float2 z1 = sp[s], z2 = sp[sp_];
        float2 A  = make_float2(0.5f * (z1.x + z2.x), 0.5f * (z1.y - z2.y));
        float2 cB = make_float2(0.5f * (z1.y + z2.y), 0.5f * (z1.x - z2.x)); // conj(B)
        float2 S  = cmul(A, cB);
        sp[s]   = make_float2(S.x * invM, -S.y * invM);   // conj(S)/M
        sp[sp_] = make_float2(S.x * invM,  S.y * invM);   // T[M-f] = S/M
    }
}

// ---- pass 2 of transform 2: column FFTs -> raw output + abs-max
__global__ __launch_bounds__(256) void fft_pass2_final(const float2* __restrict__ in,
                                                       float* __restrict__ raw,
                                                       u32* __restrict__ slot) {
    __shared__ float2 cols[2][1024];
    __shared__ float2 scr [2][1024];
    __shared__ float  wmax[4];
    const int t  = threadIdx.x;
    const int c0 = blockIdx.x * 2;               // k1' columns c0, c0+1
    const int j = t & 1, br = t >> 1;
    #pragma unroll
    for (int q = 0; q < 8; ++q) {
        int r = br + 128 * q;
        cols[j][r] = in[r * 1024 + c0 + j];
    }
    __syncthreads();
    fft1024x2(cols, scr, t);
    // out[t'] = Re(X2[k1' + 1024*k2']),  t' = (c0+jj) + 1024*k2'
    float m = 0.0f;
    #pragma unroll
    for (int q = 0; q < 8; ++q) {
        int idx = t + 256 * q;                   // jj = idx&1, k2 = idx>>1
        int jj = idx & 1, k2 = idx >> 1;
        int ot = c0 + jj + (k2 << 10);
        if (ot < N_AUDIO) {
            float v = cols[jj][k2].x;
            raw[ot] = v;
            m = fmaxf(m, fabsf(v));
        }
    }
    for (int off = 32; off > 0; off >>= 1) m = fmaxf(m, __shfl_down(m, off, 64));
    if ((t & 63) == 0) wmax[t >> 6] = m;
    __syncthreads();
    if (t == 0) {
        float b = fmaxf(fmaxf(wmax[0], wmax[1]), fmaxf(wmax[2], wmax[3]));
        atomicMax(slot, __float_as_uint(b));
    }
}

// ---- normalize
__global__ __launch_bounds__(256) void scale_k(const float* __restrict__ raw,
                                               const u32* __restrict__ slot,
                                               float* __restrict__ out) {
    int i = blockIdx.x * 256 + threadIdx.x;
    if (i < N_AUDIO) out[i] = raw[i] / __uint_as_float(*slot);
}

extern "C" void kernel_launch(void* const* d_in, const int* in_sizes, int n_in,
                              void* d_out, int out_size, void* d_ws, size_t ws_size,
                              hipStream_t stream) {
    const float* audio = (const float*)d_in[0];
    const float* ir    = (const float*)d_in[1];
    float* out = (float*)d_out;

    char* ws = (char*)d_ws;
    float2* cb0 = (float2*)(ws + OFF_C0);
    float2* cb1 = (float2*)(ws + OFF_C1);
    u32*    slot = (u32*)(ws + OFF_SLOT);

    prep_z<<<4096, 256, 0, stream>>>(audio, ir, cb0, slot);
    fft_pass1<true><<<512, 256, 0, stream>>>(cb0, cb1);        // transform 1, rows
    fft_pass2_store<<<512, 256, 0, stream>>>(cb1, cb0);        // spec (s-layout) in cb0
    pointwise<<<4096, 256, 0, stream>>>(cb0);                  // T in cb0
    fft_pass1<false><<<512, 256, 0, stream>>>(cb0, cb1);       // transform 2, rows
    fft_pass2_final<<<512, 256, 0, stream>>>(cb1, (float*)cb0, slot);
    scale_k<<<1875, 256, 0, stream>>>((const float*)cb0, slot, out);
}

// Round 9
// 112.509 us; speedup vs baseline: 3.9097x; 1.0996x over previous
//
#include <hip/hip_runtime.h>
#include <hip/hip_bf16.h>

typedef unsigned int u32;

// ---------------- FFT-based reverb (R9: fused, 5 kernels) ----------------
// out[t] = sum_k audio[t+k] ir[k], t in [0, 480000); M = 2^20 circular == linear.
// z = a + i*b ; Z = F[z]; A=(Z[f]+conj(Z[M-f]))/2, B=(Z[f]-conj(Z[M-f]))/(2i)
// S = A*conj(B); out = Re( F[ conj(S)/M ] ).
// Four-step M = 1024*1024, n = c*1024 + r: pass1 FFT over c (fixed r) + W_M^{r*k1},
// pass2 FFT over r -> X[k1 + 1024*k2], spec stored s-layout spec[k1*1024+k2] so
// transform 2's pass1 reads contiguous rows.

constexpr int N_AUDIO = 480000;
constexpr int K_IR    = 240000;
constexpr int M_FFT   = 1048576;      // 2^20

constexpr size_t OFF_C0   = 0;                    // 8 MB float2
constexpr size_t OFF_C1   = (size_t)M_FFT * 8;    // 8 MB float2
constexpr size_t OFF_SLOT = OFF_C1 + (size_t)M_FFT * 8;   // u32

__device__ __forceinline__ float2 cmul(float2 a, float2 b) {
    return make_float2(a.x * b.x - a.y * b.y, a.x * b.y + a.y * b.x);
}
__device__ __forceinline__ float2 twid(float frac) {   // e^{-2*pi*i*frac}
    float s, c;
    __sincosf(-6.28318530717958647692f * frac, &s, &c);
    return make_float2(c, s);
}

// Build stage-twiddle table: tw[L+k] = e^{-2*pi*i * k/(2L)}, L=1..512, k<L.
__device__ __forceinline__ void build_tw(float2* tw, int t) {
    for (int i = t + 1; i < 1024; i += 256) {
        int L = 1 << (31 - __builtin_clz(i));
        tw[i] = twid((float)(i - L) / (float)(2 * L));
    }
}

// radix-2 Stockham FFT-1024 in LDS, 2 rows, 256 threads, table twiddles.
// 10 stages (even) -> result back in src. (Verified R8.)
__device__ __forceinline__ void fft1024x2(float2 (*src)[1024], float2 (*scr)[1024],
                                          const float2* tw, int t) {
    float2 (*A)[1024] = src;
    float2 (*B)[1024] = scr;
    #pragma unroll
    for (int s = 0; s < 10; ++s) {
        const int L = 1 << s;
        #pragma unroll
        for (int h = 0; h < 2; ++h) {
            const int tid = t + 256 * h;
            const int k   = tid & (L - 1);
            const float2 w = tw[L + k];
            const int o0  = 2 * tid - k;
            #pragma unroll
            for (int j = 0; j < 2; ++j) {
                float2 x0 = A[j][tid];
                float2 x1 = A[j][tid + 512];
                float2 t1 = cmul(w, x1);
                B[j][o0]     = make_float2(x0.x + t1.x, x0.y + t1.y);
                B[j][o0 + L] = make_float2(x0.x - t1.x, x0.y - t1.y);
            }
        }
        __syncthreads();
        float2 (*tmp)[1024] = A; A = B; B = tmp;
    }
}

// ---- kernel A: transform-1 pass1 fused with input pack (z = audio + i*ir)
// rows r0,r0+1: z[c*1024 + r0 + j]; audio/ir read as float2 pairs along r.
__global__ __launch_bounds__(256) void fft1_pass1(const float* __restrict__ a,
                                                  const float* __restrict__ b,
                                                  float2* __restrict__ outb,
                                                  u32* __restrict__ slot) {
    __shared__ float2 rows[2][1024];
    __shared__ float2 scr [2][1024];
    __shared__ float2 tw[1024];
    const int t  = threadIdx.x;
    const int r0 = blockIdx.x * 2;
    if (blockIdx.x == 0 && t == 0) *slot = 0u;
    build_tw(tw, t);
    #pragma unroll
    for (int q = 0; q < 4; ++q) {
        int c = t + 256 * q;
        int base = c * 1024 + r0;
        float2 av = make_float2(0.f, 0.f), bv = make_float2(0.f, 0.f);
        if (c < 468 || (c == 468 && r0 < 768)) av = *(const float2*)(a + base);
        if (c < 234 || (c == 234 && r0 < 384)) bv = *(const float2*)(b + base);
        rows[0][c] = make_float2(av.x, bv.x);
        rows[1][c] = make_float2(av.y, bv.y);
    }
    __syncthreads();
    fft1024x2(rows, scr, tw, t);
    #pragma unroll
    for (int q = 0; q < 4; ++q) {
        int i2 = t + 256 * q;            // float4 idx: complex 2*i2, 2*i2+1
        int j  = i2 >> 9;
        int k1 = (i2 & 511) * 2;
        float fr = (float)(r0 + j) * (1.0f / 1048576.0f);   // exact
        float2 e0 = cmul(twid(fr * (float)k1),       rows[j][k1]);
        float2 e1 = cmul(twid(fr * (float)(k1 + 1)), rows[j][k1 + 1]);
        ((float4*)outb)[r0 * 512 + i2] = make_float4(e0.x, e0.y, e1.x, e1.y);
    }
}

// ---- kernel B: transform-1 pass2 fused with pointwise. Block handles the
// Hermitian-partner column pair {cA, cB}: block 0 -> {0,512}(self-paired),
// block b -> {b, 1024-b}. Stores T = conj(S)/M in s-layout, coalesced.
__global__ __launch_bounds__(256) void fft1_pass2_pw(const float2* __restrict__ in,
                                                     float2* __restrict__ spec) {
    __shared__ float2 cols[2][1024];
    __shared__ float2 scr [2][1024];
    __shared__ float2 tw[1024];
    const int t = threadIdx.x;
    const int bidx = blockIdx.x;
    const int cA = (bidx == 0) ? 0   : bidx;
    const int cB = (bidx == 0) ? 512 : 1024 - bidx;
    build_tw(tw, t);
    #pragma unroll
    for (int q = 0; q < 4; ++q) {
        int r = t + 256 * q;
        cols[0][r] = in[r * 1024 + cA];
        cols[1][r] = in[r * 1024 + cB];
    }
    __syncthreads();
    fft1024x2(cols, scr, tw, t);
    const float invM = 1.0f / 1048576.0f;
    #pragma unroll
    for (int q = 0; q < 4; ++q) {
        int k2 = t + 256 * q;
        #pragma unroll
        for (int j = 0; j < 2; ++j) {
            float2 z1 = cols[j][k2];                    // Z[f], f = c_j + 1024*k2
            float2 z2;                                  // Z[M-f]
            if (bidx == 0) z2 = (j == 0) ? cols[0][(1024 - k2) & 1023]
                                         : cols[1][1023 - k2];
            else           z2 = cols[j ^ 1][1023 - k2];
            float2 Af = make_float2(0.5f * (z1.x + z2.x), 0.5f * (z1.y - z2.y));
            float2 cB2 = make_float2(0.5f * (z1.y + z2.y), 0.5f * (z1.x - z2.x)); // conj(B)
            float2 S  = cmul(Af, cB2);
            int cc = (j == 0) ? cA : cB;
            spec[cc * 1024 + k2] = make_float2(S.x * invM, -S.y * invM);  // conj(S)/M
        }
    }
}

// ---- kernel C: transform-2 pass1 (contiguous rows from s-layout), float4 IO
__global__ __launch_bounds__(256) void fft2_pass1(const float2* __restrict__ in,
                                                  float2* __restrict__ outb) {
    __shared__ float2 rows[2][1024];
    __shared__ float2 scr [2][1024];
    __shared__ float2 tw[1024];
    const int t  = threadIdx.x;
    const int r0 = blockIdx.x * 2;
    build_tw(tw, t);
    const float4* inv4 = (const float4*)(in + (size_t)r0 * 1024);
    #pragma unroll
    for (int q = 0; q < 4; ++q) {
        int i2 = t + 256 * q;            // complex 2*i2, 2*i2+1
        float4 v = inv4[i2];
        int j = i2 >> 9, c = (i2 & 511) * 2;
        rows[j][c]     = make_float2(v.x, v.y);
        rows[j][c + 1] = make_float2(v.z, v.w);
    }
    __syncthreads();
    fft1024x2(rows, scr, tw, t);
    #pragma unroll
    for (int q = 0; q < 4; ++q) {
        int i2 = t + 256 * q;
        int j  = i2 >> 9;
        int k1 = (i2 & 511) * 2;
        float fr = (float)(r0 + j) * (1.0f / 1048576.0f);
        float2 e0 = cmul(twid(fr * (float)k1),       rows[j][k1]);
        float2 e1 = cmul(twid(fr * (float)(k1 + 1)), rows[j][k1 + 1]);
        ((float4*)outb)[r0 * 512 + i2] = make_float4(e0.x, e0.y, e1.x, e1.y);
    }
}

// ---- kernel D: transform-2 pass2, adjacent column pair via float4 gather,
// writes Re(out) + per-block abs-max.
__global__ __launch_bounds__(256) void fft2_pass2(const float2* __restrict__ in,
                                                  float* __restrict__ raw,
                                                  u32* __restrict__ slot) {
    __shared__ float2 cols[2][1024];
    __shared__ float2 scr [2][1024];
    __shared__ float2 tw[1024];
    __shared__ float  wmax[4];
    const int t  = threadIdx.x;
    const int c0 = blockIdx.x * 2;
    build_tw(tw, t);
    #pragma unroll
    for (int q = 0; q < 4; ++q) {
        int r = t + 256 * q;
        float4 v = *(const float4*)(in + (size_t)r * 1024 + c0);
        cols[0][r] = make_float2(v.x, v.y);
        cols[1][r] = make_float2(v.z, v.w);
    }
    __syncthreads();
    fft1024x2(cols, scr, tw, t);
    float m = 0.0f;
    #pragma unroll
    for (int q = 0; q < 8; ++q) {
        int idx = t + 256 * q;           // jj = idx&1, k2 = idx>>1
        int jj = idx & 1, k2 = idx >> 1;
        int ot = c0 + jj + (k2 << 10);
        if (ot < N_AUDIO) {
            float v = cols[jj][k2].x;
            raw[ot] = v;
            m = fmaxf(m, fabsf(v));
        }
    }
    for (int off = 32; off > 0; off >>= 1) m = fmaxf(m, __shfl_down(m, off, 64));
    if ((t & 63) == 0) wmax[t >> 6] = m;
    __syncthreads();
    if (t == 0) {
        float bm = fmaxf(fmaxf(wmax[0], wmax[1]), fmaxf(wmax[2], wmax[3]));
        atomicMax(slot, __float_as_uint(bm));
    }
}

// ---- kernel E: normalize
__global__ __launch_bounds__(256) void scale_k(const float* __restrict__ raw,
                                               const u32* __restrict__ slot,
                                               float* __restrict__ out) {
    int i = blockIdx.x * 256 + threadIdx.x;
    if (i < N_AUDIO) out[i] = raw[i] / __uint_as_float(*slot);
}

extern "C" void kernel_launch(void* const* d_in, const int* in_sizes, int n_in,
                              void* d_out, int out_size, void* d_ws, size_t ws_size,
                              hipStream_t stream) {
    const float* audio = (const float*)d_in[0];
    const float* ir    = (const float*)d_in[1];
    float* out = (float*)d_out;

    char* ws = (char*)d_ws;
    float2* cb0 = (float2*)(ws + OFF_C0);
    float2* cb1 = (float2*)(ws + OFF_C1);
    u32*    slot = (u32*)(ws + OFF_SLOT);

    fft1_pass1<<<512, 256, 0, stream>>>(audio, ir, cb1, slot);      // pack+rows
    fft1_pass2_pw<<<512, 256, 0, stream>>>(cb1, cb0);               // cols+pointwise
    fft2_pass1<<<512, 256, 0, stream>>>(cb0, cb1);                  // rows
    fft2_pass2<<<512, 256, 0, stream>>>(cb1, (float*)cb0, slot);    // cols+absmax
    scale_k<<<1875, 256, 0, stream>>>((const float*)cb0, slot, out);
}